// Round 2
// baseline (192.611 us; speedup 1.0000x reference)
//
#include <hip/hip_runtime.h>

#define OUT_H 512
#define OUT_W 512
#define BATCH 64
#define CHANS 3

__global__ __launch_bounds__(256) void st_bilinear_kernel(
    const float* __restrict__ U,      // [B, H, W, C]
    const float* __restrict__ theta,  // [B, 1]
    float* __restrict__ out)          // [B, H, W, C]
{
    // XCD-aware remap: physical blocks round-robin XCDs (blk % 8), so give
    // XCD k the logical range [k*8192, (k+1)*8192) -> images [k*8, k*8+8).
    // Each 3.1 MB image then stays resident in one XCD's 4 MB L2.
    int blk  = blockIdx.x;
    int lblk = (blk & 7) * 8192 + (blk >> 3);   // grid is 65536 blocks
    int p    = lblk * 256 + threadIdx.x;        // pixel index in [0, B*H*W)

    int j = p & (OUT_W - 1);                    // column
    int i = (p >> 9) & (OUT_H - 1);             // row
    int b = p >> 18;                            // batch (uniform per block)

    int bu = __builtin_amdgcn_readfirstlane(b); // scalar theta load
    float t = theta[bu];
    float s, c;
    sincosf(t, &s, &c);

    const float scale = 2.0f / (float)(OUT_W - 1);  // H==W==512
    float gx = (float)j * scale - 1.0f;
    float gy = (float)i * scale - 1.0f;

    // rot = [[cos, -sin, 0],[sin, cos, 0]]
    float xs = c * gx - s * gy;
    float ys = s * gx + c * gy;

    float x = (xs + 1.0f) * ((float)(OUT_W - 1) * 0.5f);
    float y = (ys + 1.0f) * ((float)(OUT_H - 1) * 0.5f);

    float x0f = floorf(x);
    float y0f = floorf(y);
    int x0 = min(max((int)x0f,     0), OUT_W - 1);
    int x1 = min(max((int)x0f + 1, 0), OUT_W - 1);
    int y0 = min(max((int)y0f,     0), OUT_H - 1);
    int y1 = min(max((int)y0f + 1, 0), OUT_H - 1);

    float fx0 = (float)x0, fx1 = (float)x1;
    float fy0 = (float)y0, fy1 = (float)y1;

    float wa = (fx1 - x) * (fy1 - y);
    float wb = (fx1 - x) * (y - fy0);
    float wc = (x - fx0) * (fy1 - y);
    float wd = (x - fx0) * (y - fy0);

    // Corners (y,x0) and (y,x1) live in 6 consecutive floats per row.
    // Load base column xb = min(x0, W-2): 6-float span never crosses a row
    // end, so never OOB. Offsets (x0-xb)*3 and (x1-xb)*3 are each 0 or 3;
    // resolve with static selects (no runtime-indexed arrays -> no scratch).
    int  xb   = min(x0, OUT_W - 2);
    bool hi_a = (x0 != xb);   // x0 channels sit at floats [3..5]
    bool hi_c = (x1 != xb);   // x1 channels sit at floats [3..5]

    const float* Ub = U + (size_t)b * (OUT_H * OUT_W * CHANS);
    const float* r0 = Ub + ((size_t)y0 * OUT_W + xb) * CHANS;
    const float* r1 = Ub + ((size_t)y1 * OUT_W + xb) * CHANS;

    // gfx950 global loads tolerate 4B alignment; addresses are 4B-aligned.
    float4 r0lo = *(const float4*)(r0);
    float2 r0hi = *(const float2*)(r0 + 4);
    float4 r1lo = *(const float4*)(r1);
    float2 r1hi = *(const float2*)(r1 + 4);

    // Ia = U[y0,x0], Ic = U[y0,x1]  (row y0)
    float a0 = hi_a ? r0lo.w : r0lo.x;
    float a1 = hi_a ? r0hi.x : r0lo.y;
    float a2 = hi_a ? r0hi.y : r0lo.z;
    float c0 = hi_c ? r0lo.w : r0lo.x;
    float c1 = hi_c ? r0hi.x : r0lo.y;
    float c2 = hi_c ? r0hi.y : r0lo.z;
    // Ib = U[y1,x0], Id = U[y1,x1]  (row y1)
    float b0 = hi_a ? r1lo.w : r1lo.x;
    float b1 = hi_a ? r1hi.x : r1lo.y;
    float b2 = hi_a ? r1hi.y : r1lo.z;
    float d0 = hi_c ? r1lo.w : r1lo.x;
    float d1 = hi_c ? r1hi.x : r1lo.y;
    float d2 = hi_c ? r1hi.y : r1lo.z;

    float* po = out + (size_t)p * CHANS;
    po[0] = wa * a0 + wb * b0 + wc * c0 + wd * d0;
    po[1] = wa * a1 + wb * b1 + wc * c1 + wd * d1;
    po[2] = wa * a2 + wb * b2 + wc * c2 + wd * d2;
}

extern "C" void kernel_launch(void* const* d_in, const int* in_sizes, int n_in,
                              void* d_out, int out_size, void* d_ws, size_t ws_size,
                              hipStream_t stream) {
    const float* U     = (const float*)d_in[0];
    const float* theta = (const float*)d_in[1];
    float* out = (float*)d_out;

    int total_pixels = BATCH * OUT_H * OUT_W;      // 16,777,216
    int blocks = total_pixels / 256;               // 65,536
    st_bilinear_kernel<<<blocks, 256, 0, stream>>>(U, theta, out);
}

// Round 3
// 114.231 us; speedup vs baseline: 1.6862x; 1.6862x over previous
//
#include <hip/hip_runtime.h>

#define OUT_H 512
#define OUT_W 512
#define BATCH 64
#define CHANS 3

__global__ __launch_bounds__(256) void st_bilinear_kernel(
    const float* __restrict__ U,      // [B, H, W, C]
    const float* __restrict__ theta,  // [B, 1]
    float* __restrict__ out)          // [B, H, W, C]
{
    // XCD-aware remap: physical blocks round-robin XCDs (blk % 8); give XCD k
    // the logical range [k*8192, (k+1)*8192) -> images [k*8, k*8+8) so each
    // 3.1 MB image stays resident in one XCD's 4 MB L2.
    int blk  = blockIdx.x;
    int lblk = (blk & 7) * 8192 + (blk >> 3);   // grid is 65536 blocks

    // 1024 blocks per image; each block = 16x16 pixel tile (32x32 tiles/img).
    int b  = lblk >> 10;                        // image (uniform per block)
    int t  = lblk & 1023;
    int tr = t >> 5;                            // tile row
    int tc = t & 31;                            // tile col

    // Wave = 8x8 quadrant of the 16x16 tile: minimizes the rotated source
    // footprint per wave (<= ~11 rows x ~11 cols) -> few L1 lines per gather.
    int lane = threadIdx.x & 63;
    int wv   = threadIdx.x >> 6;
    int i = (tr << 4) + ((wv >> 1) << 3) + (lane >> 3);   // output row
    int j = (tc << 4) + ((wv & 1) << 3) + (lane & 7);     // output col

    int bu = __builtin_amdgcn_readfirstlane(b);
    float tt = theta[bu];
    float s, c;
    __sincosf(tt, &s, &c);

    const float scale = 2.0f / (float)(OUT_W - 1);  // H==W==512
    float gx = (float)j * scale - 1.0f;
    float gy = (float)i * scale - 1.0f;

    // rot = [[cos, -sin, 0],[sin, cos, 0]]
    float xs = c * gx - s * gy;
    float ys = s * gx + c * gy;

    float x = (xs + 1.0f) * ((float)(OUT_W - 1) * 0.5f);
    float y = (ys + 1.0f) * ((float)(OUT_H - 1) * 0.5f);

    float x0f = floorf(x);
    float y0f = floorf(y);
    int x0 = min(max((int)x0f,     0), OUT_W - 1);
    int x1 = min(max((int)x0f + 1, 0), OUT_W - 1);
    int y0 = min(max((int)y0f,     0), OUT_H - 1);
    int y1 = min(max((int)y0f + 1, 0), OUT_H - 1);

    float fx0 = (float)x0, fx1 = (float)x1;
    float fy0 = (float)y0, fy1 = (float)y1;

    float wa = (fx1 - x) * (fy1 - y);
    float wb = (fx1 - x) * (y - fy0);
    float wc = (x - fx0) * (fy1 - y);
    float wd = (x - fx0) * (y - fy0);

    // Corners (y,x0) and (y,x1) span 6 consecutive floats per source row.
    // Base column xb = min(x0, W-2): the 6-float span never crosses a row
    // end. x0/x1 sit at float offset 0 or 3 -> static selects, no scratch.
    int  xb   = min(x0, OUT_W - 2);
    bool hi_a = (x0 != xb);
    bool hi_c = (x1 != xb);

    const float* Ub = U + (size_t)b * (OUT_H * OUT_W * CHANS);
    const float* r0 = Ub + ((size_t)y0 * OUT_W + xb) * CHANS;
    const float* r1 = Ub + ((size_t)y1 * OUT_W + xb) * CHANS;

    float4 r0lo = *(const float4*)(r0);
    float2 r0hi = *(const float2*)(r0 + 4);
    float4 r1lo = *(const float4*)(r1);
    float2 r1hi = *(const float2*)(r1 + 4);

    float a0 = hi_a ? r0lo.w : r0lo.x;
    float a1 = hi_a ? r0hi.x : r0lo.y;
    float a2 = hi_a ? r0hi.y : r0lo.z;
    float c0 = hi_c ? r0lo.w : r0lo.x;
    float c1 = hi_c ? r0hi.x : r0lo.y;
    float c2 = hi_c ? r0hi.y : r0lo.z;
    float b0 = hi_a ? r1lo.w : r1lo.x;
    float b1 = hi_a ? r1hi.x : r1lo.y;
    float b2 = hi_a ? r1hi.y : r1lo.z;
    float d0 = hi_c ? r1lo.w : r1lo.x;
    float d1 = hi_c ? r1hi.x : r1lo.y;
    float d2 = hi_c ? r1hi.y : r1lo.z;

    size_t pix = ((size_t)b * OUT_H + i) * OUT_W + j;
    float* po = out + pix * CHANS;
    po[0] = wa * a0 + wb * b0 + wc * c0 + wd * d0;
    po[1] = wa * a1 + wb * b1 + wc * c1 + wd * d1;
    po[2] = wa * a2 + wb * b2 + wc * c2 + wd * d2;
}

extern "C" void kernel_launch(void* const* d_in, const int* in_sizes, int n_in,
                              void* d_out, int out_size, void* d_ws, size_t ws_size,
                              hipStream_t stream) {
    const float* U     = (const float*)d_in[0];
    const float* theta = (const float*)d_in[1];
    float* out = (float*)d_out;

    int total_pixels = BATCH * OUT_H * OUT_W;      // 16,777,216
    int blocks = total_pixels / 256;               // 65,536
    st_bilinear_kernel<<<blocks, 256, 0, stream>>>(U, theta, out);
}

// Round 4
// 105.568 us; speedup vs baseline: 1.8245x; 1.0821x over previous
//
#include <hip/hip_runtime.h>

#define OUT_H 512
#define OUT_W 512
#define BATCH 64
#define CHANS 3

// LDS window: 47 rows x 37 float4 (= 148 dwords = 49.33 px). Loaded region:
// 46 rows x 144 dwords (48 px). Row 46 / cols 144..147 are read only by
// degenerate (masked-to-zero) pixels and never written.
#define LROWS 47
#define LROW_F4 37           // float4 per row
#define LROW_DW 148          // dwords per row

__global__ __launch_bounds__(256) void st_bilinear_kernel(
    const float* __restrict__ U,      // [B, H, W, C]
    const float* __restrict__ theta,  // [B, 1]
    float* __restrict__ out)          // [B, H, W, C]
{
    __shared__ float4 smem4[LROWS * LROW_F4];

    // XCD-aware remap: 16384 blocks; give XCD k images [k*8, k*8+8) so each
    // 3.1 MB image stays in one XCD's 4 MB L2.
    int blk  = blockIdx.x;
    int lblk = (blk & 7) * 2048 + (blk >> 3);

    int b  = lblk >> 8;                 // image (uniform per block)
    int t  = lblk & 255;                // 16x16 tiles of 32x32 px
    int i0 = (t >> 4) << 5;             // tile row origin
    int j0 = (t & 15) << 5;             // tile col origin

    int tid = threadIdx.x;

    float tt = theta[b];
    float s, c;
    __sincosf(tt, &s, &c);

    // x = xb0 + c*jl - s*il ; y = yb0 + s*jl + c*il   (dx/dj == c exactly:
    // (2/511)*255.5 == 1)
    const float scale = 2.0f / 511.0f;
    float gx0 = (float)j0 * scale - 1.0f;
    float gy0 = (float)i0 * scale - 1.0f;
    float xb0 = (c * gx0 - s * gy0 + 1.0f) * 255.5f;
    float yb0 = (s * gx0 + c * gy0 + 1.0f) * 255.5f;

    // Source bbox of this 32x32 tile (linear map -> corner extremes).
    float xmin = xb0 + fminf(0.0f, 31.0f * c) + fminf(0.0f, -31.0f * s);
    float ymin = yb0 + fminf(0.0f, 31.0f * s) + fminf(0.0f,  31.0f * c);

    int bx0 = min(max((int)floorf(xmin), 0), OUT_W - 1);
    int by0 = min(max((int)floorf(ymin), 0), OUT_H - 1);
    // Clamp load origin so the fixed 48 px x 46 row window stays in-image.
    int bx_load = min(bx0, OUT_W - 48);   // 464
    int by_load = min(by0, OUT_H - 46);   // 466

    // Stage 46 rows x 144 dwords, coalesced float4 (4B-aligned is fine on
    // gfx950). 46*36 = 1656 float4 per block.
    const float* Ub = U + (size_t)b * (OUT_H * OUT_W * CHANS);
    const float* gbase = Ub + (size_t)by_load * (OUT_W * CHANS) + bx_load * CHANS;
    for (int u = tid; u < 46 * 36; u += 256) {
        int r  = u / 36;                 // magic-mul
        int c4 = u - r * 36;
        float4 v = *(const float4*)(gbase + (size_t)r * (OUT_W * CHANS) + c4 * 4);
        smem4[r * LROW_F4 + c4] = v;
    }
    __syncthreads();

    const float* lds = (const float*)smem4;

    // 4 iterations: each covers 8 output rows x 32 cols.
    int jl = tid & 31;
    int il_base = tid >> 5;
#pragma unroll
    for (int k = 0; k < 4; ++k) {
        int il = (k << 3) + il_base;
        float x = xb0 + c * (float)jl - s * (float)il;
        float y = yb0 + s * (float)jl + c * (float)il;

        float x0f = floorf(x);
        float y0f = floorf(y);
        float fx = x - x0f;              // frac
        float fy = y - y0f;
        float hx1 = 1.0f - fx;
        float hy1 = 1.0f - fy;
        float wa = hx1 * hy1;            // (y0,x0)
        float wb = hx1 * fy;             // (y1,x0)
        float wc = fx * hy1;             // (y0,x1)
        float wd = fx * fy;              // (y1,x1)

        int x0c = min(max((int)x0f, 0), OUT_W - 1);
        int y0c = min(max((int)y0f, 0), OUT_H - 1);
        int lx = x0c - bx_load;          // [0,47]
        int ly = y0c - by_load;          // [0,45]

        const float* lp = lds + ly * LROW_DW + lx * CHANS;
        // 12 dword reads, 6 ds_read2_b32-mergeable pairs, one shared base.
        float v00_0 = lp[0],   v01_0 = lp[3];
        float v00_1 = lp[1],   v01_1 = lp[4];
        float v00_2 = lp[2],   v01_2 = lp[5];
        float v10_0 = lp[LROW_DW + 0], v11_0 = lp[LROW_DW + 3];
        float v10_1 = lp[LROW_DW + 1], v11_1 = lp[LROW_DW + 4];
        float v10_2 = lp[LROW_DW + 2], v11_2 = lp[LROW_DW + 5];

        float r0 = wa * v00_0 + wc * v01_0 + wb * v10_0 + wd * v11_0;
        float r1 = wa * v00_1 + wc * v01_1 + wb * v10_1 + wd * v11_1;
        float r2 = wa * v00_2 + wc * v01_2 + wb * v10_2 + wd * v11_2;

        // Reference yields exactly 0 where the clamped corner pair collapses
        // (x<0, x>=511, y<0, y>=511). Select (NaN-safe vs garbage LDS).
        bool valid = (x >= 0.0f) && (x < 511.0f) && (y >= 0.0f) && (y < 511.0f);
        r0 = valid ? r0 : 0.0f;
        r1 = valid ? r1 : 0.0f;
        r2 = valid ? r2 : 0.0f;

        float* po = out + (((size_t)b * OUT_H + (i0 + il)) * OUT_W + (j0 + jl)) * CHANS;
        po[0] = r0;
        po[1] = r1;
        po[2] = r2;
    }
}

extern "C" void kernel_launch(void* const* d_in, const int* in_sizes, int n_in,
                              void* d_out, int out_size, void* d_ws, size_t ws_size,
                              hipStream_t stream) {
    const float* U     = (const float*)d_in[0];
    const float* theta = (const float*)d_in[1];
    float* out = (float*)d_out;

    int blocks = BATCH * (OUT_H / 32) * (OUT_W / 32);   // 16384
    st_bilinear_kernel<<<blocks, 256, 0, stream>>>(U, theta, out);
}